// Round 1
// baseline (1930.772 us; speedup 1.0000x reference)
//
#include <hip/hip_runtime.h>
#include <cmath>

// ConceptLearner LSTM on MI355X.
// Sizes: B=64, S=128, D=64, H=256 (4H=1024 gates), P=1024, V*R=32000.
// 128 independent chains (2 encodes x 64 batch). Recurrence: 8 blocks x 16 chains,
// f16 MFMA 16x16x32 with Whh resident in VGPRs (i/f/g tiles) + LDS (o tiles).

typedef _Float16 f16;
typedef _Float16 f16x8 __attribute__((ext_vector_type(8)));
typedef float f32x4 __attribute__((ext_vector_type(4)));

#define MFMA(a,b,c) __builtin_amdgcn_mfma_f32_16x16x32_f16((a),(b),(c),0,0,0)

__device__ __forceinline__ float sigf(float x)  { return 1.f/(1.f+__expf(-x)); }
__device__ __forceinline__ float tanhf_(float x){ return 1.f - 2.f/(__expf(2.f*x)+1.f); }

// ---------------------------------------------------------------- convert ---
__global__ void k_convert(const float* __restrict__ x1, const float* __restrict__ x2,
                          const float* __restrict__ Wih0, const float* __restrict__ Whh0,
                          const float* __restrict__ bih0, const float* __restrict__ bhh0,
                          const float* __restrict__ Wih1, const float* __restrict__ Whh1,
                          const float* __restrict__ bih1, const float* __restrict__ bhh1,
                          f16* __restrict__ x16, f16* __restrict__ w16, float* __restrict__ bsum)
{
    int i = blockIdx.x * 256 + threadIdx.x;           // grid 2048*256
    if (i < 524288) { x16[i] = (f16)x1[i]; x16[524288 + i] = (f16)x2[i]; }
    if (i < 65536)  w16[i] = (f16)Wih0[i];            // Wih0 [1024][64]
    if (i < 262144) {
        w16[65536  + i] = (f16)Whh0[i];               // Whh0 [1024][256]
        w16[327680 + i] = (f16)Wih1[i];               // Wih1 [1024][256]
        w16[589824 + i] = (f16)Whh1[i];               // Whh1 [1024][256]
    }
    if (i < 1024) { bsum[i] = bih0[i] + bhh0[i]; bsum[1024 + i] = bih1[i] + bhh1[i]; }
}

// ------------------------------------------------- input projection (MFMA) --
// out[m][n] = sum_k A[m][k]*Bw[n][k] + bias[n].  M=16384 rows=(e,b,s), N=1024.
template<int K>
__global__ __launch_bounds__(512)
void k_proj(const f16* __restrict__ A, const f16* __restrict__ Bw,
            const float* __restrict__ bias, float* __restrict__ out)
{
    const int w = threadIdx.x >> 6, lane = threadIdx.x & 63;
    const int quad = lane >> 4, l16 = lane & 15;
    const long m0 = (long)blockIdx.x * 128 + w * 16;   // wave's M-tile
    const int  n0 = blockIdx.y * 128;
    f32x4 acc[8] = {};
    #pragma unroll
    for (int kc = 0; kc < K/32; ++kc) {
        const int ko = kc*32 + quad*8;
        f16x8 a = *(const f16x8*)(A + (m0 + l16)*K + ko);           // A[m=lane&15][k]
        #pragma unroll
        for (int nt = 0; nt < 8; ++nt) {
            f16x8 b = *(const f16x8*)(Bw + (long)(n0 + nt*16 + l16)*K + ko); // B[n][k]
            acc[nt] = MFMA(a, b, acc[nt]);
        }
    }
    #pragma unroll
    for (int nt = 0; nt < 8; ++nt)
        #pragma unroll
        for (int r = 0; r < 4; ++r) {                  // D: row=quad*4+r, col=lane&15
            long mm = m0 + quad*4 + r;
            int  nn = n0 + nt*16 + l16;
            out[mm*1024 + nn] = acc[nt][r] + bias[nn];
        }
}

// ------------------------------------------------------- LSTM recurrence ----
// 8 blocks x 512 thr (8 waves). Block = (encode e, 16-chain group c0).
// Wave w owns gate tiles {2w,2w+1} (i), {+16} (f), {+32} (g) in VGPRs, {+48} (o) in LDS.
// Gate quartet per (col j, chain): all four gates land in the same lane -> in-reg mixing.
template<int LAYER>
__global__ __launch_bounds__(512, 2)
void k_lstm(const f16* __restrict__ Whh, const float* __restrict__ xg,
            f16* __restrict__ hs0, float* __restrict__ out_enc)
{
    __shared__ f16 wl[16*16*264];   // o-gate rows 768..1023, row stride 264 (pad: 2-way-free banks)
    __shared__ f16 hb[2*16*264];    // double-buffered h (f16), rows = chains
    const int tid = threadIdx.x;
    const int w = tid >> 6, lane = tid & 63;
    const int quad = lane >> 4, l16 = lane & 15;
    const int e = blockIdx.x >> 2, c0 = (blockIdx.x & 3) * 16;

    // resident b-frags: slots {i:0,1  f:2,3  g:4,5}; tile = (slot>>1)*16 + 2w + (slot&1)
    f16x8 bres[6][8];
    #pragma unroll
    for (int s6 = 0; s6 < 6; ++s6) {
        const int tile = (s6 >> 1)*16 + 2*w + (s6 & 1);
        #pragma unroll
        for (int kc = 0; kc < 8; ++kc)
            bres[s6][kc] = *(const f16x8*)(Whh + (tile*16 + l16)*256 + kc*32 + quad*8);
    }
    {   // stage o-gate rows into LDS (coalesced, once)
        const int r = tid >> 1, hh = tid & 1;
        const f16* src = Whh + (768 + r)*256 + hh*128;
        f16* dst = wl + r*264 + hh*128;
        #pragma unroll
        for (int j = 0; j < 16; ++j)
            *(f16x8*)(dst + j*8) = *(const f16x8*)(src + j*8);
    }
    for (int i = tid; i < 2*16*264; i += 512) hb[i] = (f16)0.f;   // h(-1)=0

    float c[8]    = {0,0,0,0,0,0,0,0};
    float oacc[8] = {0,0,0,0,0,0,0,0};
    __syncthreads();

    #pragma unroll 1
    for (int s = 0; s < 128; ++s) {
        const int rb = s & 1, wb = rb ^ 1;
        #pragma unroll
        for (int q = 0; q < 2; ++q) {
            const int ti = 2*w + q;                     // i-tile index = h-col block
            // xg preacts (fp32, global); latency hidden under the 32 MFMAs below
            float xi[4], xf[4], xgv[4], xo[4];
            #pragma unroll
            for (int r = 0; r < 4; ++r) {
                const float* xp = xg + ((long)(e*64 + c0 + quad*4 + r)*128 + s)*1024 + ti*16 + l16;
                xi[r] = xp[0]; xf[r] = xp[256]; xgv[r] = xp[512]; xo[r] = xp[768];
            }
            f32x4 ai = {}, af = {}, ag = {}, ao = {};
            #pragma unroll
            for (int kc = 0; kc < 8; ++kc) {
                f16x8 a  = *(const f16x8*)(hb + (rb*16 + l16)*264 + kc*32 + quad*8);
                f16x8 bo = *(const f16x8*)(wl + (ti*16 + l16)*264 + kc*32 + quad*8);
                ai = MFMA(a, bres[q][kc],   ai);
                af = MFMA(a, bres[2+q][kc], af);
                ag = MFMA(a, bres[4+q][kc], ag);
                ao = MFMA(a, bo,            ao);
            }
            #pragma unroll
            for (int r = 0; r < 4; ++r) {
                float gi = sigf(ai[r] + xi[r]);
                float gf = sigf(af[r] + xf[r]);
                float gg = tanhf_(ag[r] + xgv[r]);
                float go = sigf(ao[r] + xo[r]);
                const int ci = q*4 + r;
                float cn = gf*c[ci] + gi*gg;
                c[ci] = cn;
                float hn = go * tanhf_(cn);
                if (LAYER == 1) oacc[ci] += hn;
                hb[(wb*16 + quad*4 + r)*264 + ti*16 + l16] = (f16)hn;
            }
        }
        __syncthreads();
        if (LAYER == 0) {   // coalesced h(s) -> hs0 for the layer-1 input projection
            const int cc = tid >> 5, kk = (tid & 31) * 8;
            f16x8 hv = *(const f16x8*)(hb + (wb*16 + cc)*264 + kk);
            *(f16x8*)(hs0 + ((long)(e*64 + c0 + cc)*128 + s)*256 + kk) = hv;
        }
    }
    if (LAYER == 1) {       // time-summed hidden state -> encoder output
        #pragma unroll
        for (int q = 0; q < 2; ++q)
            #pragma unroll
            for (int r = 0; r < 4; ++r)
                out_enc[(long)(e*64 + c0 + quad*4 + r)*256 + (2*w+q)*16 + l16] = oacc[q*4 + r];
    }
}

// ----------------------------------------------------- fp32 FC (head) -------
// Block: [64 rows x 32 cols]; W staged in LDS (broadcast reads), A staged transposed.
// MODE 0: gelu (A = concat(enc0,enc1)); MODE 1: res + relu; MODE 2: relu (scores).
template<int K, int MODE>
__global__ __launch_bounds__(256)
void k_fc(const float* __restrict__ A, const float* __restrict__ W,
          const float* __restrict__ bias, const float* __restrict__ res,
          float* __restrict__ out, const int Nst)
{
    __shared__ float ws[32*64];
    __shared__ float as[64*64];   // [k][m] -> conflict-free compute reads
    const int tid = threadIdx.x;
    const int n0 = blockIdx.x * 32;
    const int m2 = tid & 31, ndg = tid >> 5;
    float acc[2][4] = {};
    for (int kc = 0; kc < K/64; ++kc) {
        __syncthreads();
        {   // stage W [32 cols][64 k]
            const int col = tid >> 3, k8 = (tid & 7)*8;
            const float* src = W + (long)(n0 + col)*K + kc*64 + k8;
            *(float4*)(ws + col*64 + k8)     = *(const float4*)(src);
            *(float4*)(ws + col*64 + k8 + 4) = *(const float4*)(src + 4);
        }
        {   // stage A transposed: as[k][m]
            const int m = tid >> 2, j4 = (tid & 3)*16;
            #pragma unroll
            for (int i4 = 0; i4 < 4; ++i4) {
                const int kk = kc*64 + j4 + i4*4;
                const float* srcA;
                if (MODE == 0) srcA = (kk < 256) ? (A + (long)m*256 + kk)
                                                 : (A + 16384 + (long)m*256 + kk - 256);
                else           srcA = A + (long)m*K + kk;
                float4 v = *(const float4*)srcA;
                as[(j4 + i4*4 + 0)*64 + m] = v.x;
                as[(j4 + i4*4 + 1)*64 + m] = v.y;
                as[(j4 + i4*4 + 2)*64 + m] = v.z;
                as[(j4 + i4*4 + 3)*64 + m] = v.w;
            }
        }
        __syncthreads();
        #pragma unroll 4
        for (int k4 = 0; k4 < 64; k4 += 4) {
            float a0[4], a1[4];
            #pragma unroll
            for (int i = 0; i < 4; ++i) {
                a0[i] = as[(k4+i)*64 + m2];
                a1[i] = as[(k4+i)*64 + m2 + 32];
            }
            #pragma unroll
            for (int j = 0; j < 4; ++j) {
                const float4 wv = *(const float4*)(ws + (ndg*4 + j)*64 + k4);
                acc[0][j] += a0[0]*wv.x + a0[1]*wv.y + a0[2]*wv.z + a0[3]*wv.w;
                acc[1][j] += a1[0]*wv.x + a1[1]*wv.y + a1[2]*wv.z + a1[3]*wv.w;
            }
        }
    }
    #pragma unroll
    for (int i = 0; i < 2; ++i) {
        const int m = m2 + i*32;
        #pragma unroll
        for (int j = 0; j < 4; ++j) {
            const int nn = n0 + ndg*4 + j;
            float v = acc[i][j] + bias[nn];
            if (MODE == 0)      v = 0.5f * v * (1.0f + erff(v * 0.7071067811865475f));
            else if (MODE == 1) v = res[(long)m*1024 + nn] + fmaxf(v, 0.f);
            else                v = fmaxf(v, 0.f);
            out[(long)m*Nst + nn] = v;
        }
    }
}

// ---------------------------------------------------------- batchnorm -------
__global__ void k_bn(const float* __restrict__ h2, const float* __restrict__ g,
                     const float* __restrict__ b, float* __restrict__ h3)
{
    const int col = blockIdx.x*256 + threadIdx.x;     // 4 blocks x 256 = 1024 cols
    float s = 0.f, ss = 0.f;
    for (int m = 0; m < 64; ++m) { float v = h2[m*1024 + col]; s += v; ss += v*v; }
    const float mu  = s * (1.f/64.f);
    const float var = ss * (1.f/64.f) - mu*mu;
    const float rs  = rsqrtf(var + 1e-5f);
    const float gg = g[col], bb = b[col];
    for (int m = 0; m < 64; ++m) {
        float v = h2[m*1024 + col];
        h3[m*1024 + col] = (v - mu)*rs*gg + bb;
    }
}

// ---------------------------------------------------------- count -----------
__global__ void k_count(const float* __restrict__ scores, float* __restrict__ outc)
{
    const int row = blockIdx.x, tid = threadIdx.x;
    const float* p = scores + (long)row*32000;
    int cnt = 0;
    for (int i = tid; i < 32000; i += 256)
        cnt += ((double)p[i] > 0.6400000000000001) ? 1 : 0;   // match np f64 threshold
    __shared__ int red[256];
    red[tid] = cnt; __syncthreads();
    for (int off = 128; off > 0; off >>= 1) {
        if (tid < off) red[tid] += red[tid + off];
        __syncthreads();
    }
    if (tid == 0) outc[row] = (float)(red[0] < 1 ? 1 : red[0]);
}

// ---------------------------------------------------------- launch ----------
extern "C" void kernel_launch(void* const* d_in, const int* in_sizes, int n_in,
                              void* d_out, int out_size, void* d_ws, size_t ws_size,
                              hipStream_t stream)
{
    const float* x1    = (const float*)d_in[0];
    const float* x2    = (const float*)d_in[1];
    const float* Wih0  = (const float*)d_in[2];
    const float* Whh0  = (const float*)d_in[3];
    const float* bih0  = (const float*)d_in[4];
    const float* bhh0  = (const float*)d_in[5];
    const float* Wih1  = (const float*)d_in[6];
    const float* Whh1  = (const float*)d_in[7];
    const float* bih1  = (const float*)d_in[8];
    const float* bhh1  = (const float*)d_in[9];
    const float* fc1_w = (const float*)d_in[10];
    const float* fc1_b = (const float*)d_in[11];
    const float* fc2_w = (const float*)d_in[12];
    const float* fc2_b = (const float*)d_in[13];
    const float* fc3_w = (const float*)d_in[14];
    const float* fc3_b = (const float*)d_in[15];
    const float* bn_g  = (const float*)d_in[16];
    const float* bn_b  = (const float*)d_in[17];
    float* out = (float*)d_out;

    char* ws = (char*)d_ws;                 // total workspace use: 80,224,256 B
    f16*   x16  = (f16*)(ws);               // [2][64][128][64] f16
    f16*   w16  = (f16*)(ws + 2097152);     // Wih0 | Whh0 | Wih1 | Whh1 (f16)
    float* bsum = (float*)(ws + 3801088);   // bih0+bhh0 | bih1+bhh1
    f16*   hs0  = (f16*)(ws + 3809280);     // [2][64][128][256] f16
    float* xg   = (float*)(ws + 12197888);  // [2][64][128][1024] f32 (xg0 then xg1)
    float* enc  = (float*)(ws + 79306752);  // [2][64][256] f32
    float* h1   = (float*)(ws + 79437824);  // [64][1024]
    float* h2   = (float*)(ws + 79699968);
    float* h3   = (float*)(ws + 79962112);

    k_convert<<<2048, 256, 0, stream>>>(x1,x2,Wih0,Whh0,bih0,bhh0,Wih1,Whh1,bih1,bhh1,
                                        x16, w16, bsum);
    // xg0 = x @ Wih0^T + (bih0+bhh0)
    k_proj<64><<<dim3(128,8), 512, 0, stream>>>(x16, w16, bsum, xg);
    // layer-0 recurrence, writes hs0 (f16)
    k_lstm<0><<<8, 512, 0, stream>>>(w16 + 65536, xg, hs0, nullptr);
    // xg1 = hs0 @ Wih1^T + (bih1+bhh1)  (reuses xg buffer)
    k_proj<256><<<dim3(128,8), 512, 0, stream>>>(hs0, w16 + 327680, bsum + 1024, xg);
    // layer-1 recurrence + time-sum -> enc
    k_lstm<1><<<8, 512, 0, stream>>>(w16 + 589824, xg, nullptr, enc);
    // head
    k_fc<512,0><<<32, 256, 0, stream>>>(enc, fc1_w, fc1_b, nullptr, h1, 1024);
    k_fc<1024,1><<<32, 256, 0, stream>>>(h1, fc2_w, fc2_b, h1, h2, 1024);
    k_bn<<<4, 256, 0, stream>>>(h2, bn_g, bn_b, h3);
    k_fc<1024,2><<<1000, 256, 0, stream>>>(h3, fc3_w, fc3_b, nullptr, out, 32000);
    k_count<<<64, 256, 0, stream>>>(out, out + 2048000);
}

// Round 2
// 1232.233 us; speedup vs baseline: 1.5669x; 1.5669x over previous
//
#include <hip/hip_runtime.h>
#include <cmath>

// ConceptLearner LSTM on MI355X.
// Sizes: B=64, S=128, D=64, H=256 (4H=1024 gates), P=1024, V*R=32000.
// 128 independent chains (2 encodes x 64 batch). Recurrence: 8 blocks x 16 chains,
// f16 MFMA 16x16x32 with Whh resident in VGPRs/AGPRs (i/f/g tiles) + LDS (o tiles).
// R1: LDS stride 280 (132dw->140dw, 2-way free), fast rcp in activations,
//     xg stored f16 gate-interleaved [chain][s][ti][col][ifgo] -> 1 f16x4 load/(q,r),
//     hs0 write moved off the barrier critical path.

typedef _Float16 f16;
typedef _Float16 f16x8 __attribute__((ext_vector_type(8)));
typedef _Float16 f16x4 __attribute__((ext_vector_type(4)));
typedef float f32x4 __attribute__((ext_vector_type(4)));

#define MFMA(a,b,c) __builtin_amdgcn_mfma_f32_16x16x32_f16((a),(b),(c),0,0,0)
#define LSTR 280   // LDS row stride in f16: 140 dwords, 140%32=12 -> 2-way (free)

__device__ __forceinline__ float frcp(float x) { return __builtin_amdgcn_rcpf(x); }
__device__ __forceinline__ float sigf(float x)  { return frcp(1.f + __expf(-x)); }
__device__ __forceinline__ float tanhf_(float x){ return 1.f - 2.f*frcp(__expf(2.f*x) + 1.f); }

// ---------------------------------------------------------------- convert ---
__global__ void k_convert(const float* __restrict__ x1, const float* __restrict__ x2,
                          const float* __restrict__ Wih0, const float* __restrict__ Whh0,
                          const float* __restrict__ bih0, const float* __restrict__ bhh0,
                          const float* __restrict__ Wih1, const float* __restrict__ Whh1,
                          const float* __restrict__ bih1, const float* __restrict__ bhh1,
                          f16* __restrict__ x16, f16* __restrict__ w16, float* __restrict__ bsum)
{
    int i = blockIdx.x * 256 + threadIdx.x;           // grid 2048*256
    if (i < 524288) { x16[i] = (f16)x1[i]; x16[524288 + i] = (f16)x2[i]; }
    if (i < 65536)  w16[i] = (f16)Wih0[i];            // Wih0 [1024][64]
    if (i < 262144) {
        w16[65536  + i] = (f16)Whh0[i];               // Whh0 [1024][256]
        w16[327680 + i] = (f16)Wih1[i];               // Wih1 [1024][256]
        w16[589824 + i] = (f16)Whh1[i];               // Whh1 [1024][256]
    }
    if (i < 1024) { bsum[i] = bih0[i] + bhh0[i]; bsum[1024 + i] = bih1[i] + bhh1[i]; }
}

// ------------------------------------------------- input projection (MFMA) --
// out preacts stored f16, gate-interleaved: [chain(m)][1024] where within a row
// offset = ti*64 + col*4 + gate  (ti=h-col tile 0..15, col 0..15, gate i/f/g/o).
// Block covers ti pair {2*by, 2*by+1} across all 4 gates. M=16384 rows=(e,b,s).
template<int K>
__global__ __launch_bounds__(512)
void k_proj(const f16* __restrict__ A, const f16* __restrict__ Bw,
            const float* __restrict__ bias, f16* __restrict__ out)
{
    const int w = threadIdx.x >> 6, lane = threadIdx.x & 63;
    const int quad = lane >> 4, l16 = lane & 15;
    const long m0 = (long)blockIdx.x * 128 + w * 16;   // wave's M-tile
    f32x4 acc[2][4] = {};
    #pragma unroll
    for (int kc = 0; kc < K/32; ++kc) {
        const int ko = kc*32 + quad*8;
        f16x8 a = *(const f16x8*)(A + (m0 + l16)*K + ko);           // A[m=lane&15][k]
        #pragma unroll
        for (int tg = 0; tg < 2; ++tg) {
            const int ti = blockIdx.y*2 + tg;
            #pragma unroll
            for (int g = 0; g < 4; ++g) {
                f16x8 b = *(const f16x8*)(Bw + (long)(g*256 + ti*16 + l16)*K + ko);
                acc[tg][g] = MFMA(a, b, acc[tg][g]);
            }
        }
    }
    #pragma unroll
    for (int tg = 0; tg < 2; ++tg) {
        const int ti = blockIdx.y*2 + tg;
        float bi[4];
        #pragma unroll
        for (int g = 0; g < 4; ++g) bi[g] = bias[g*256 + ti*16 + l16];
        #pragma unroll
        for (int r = 0; r < 4; ++r) {                  // D: row=quad*4+r, col=lane&15
            long mm = m0 + quad*4 + r;
            f16x4 pv;
            #pragma unroll
            for (int g = 0; g < 4; ++g) pv[g] = (f16)(acc[tg][g][r] + bi[g]);
            *(f16x4*)(out + mm*1024 + ti*64 + l16*4) = pv;
        }
    }
}

// ------------------------------------------------------- LSTM recurrence ----
// 8 blocks x 512 thr (8 waves). Block = (encode e, 16-chain group c0).
// Wave w owns gate tiles {2w,2w+1} (i), {+16} (f), {+32} (g) in regs, {+48} (o) in LDS.
template<int LAYER>
__global__ __launch_bounds__(512, 2)
void k_lstm(const f16* __restrict__ Whh, const f16* __restrict__ xg,
            f16* __restrict__ hs0, float* __restrict__ out_enc)
{
    __shared__ f16 wl[256*LSTR];    // o-gate rows 768..1023
    __shared__ f16 hb[2*16*LSTR];   // double-buffered h (f16), rows = chains
    const int tid = threadIdx.x;
    const int w = tid >> 6, lane = tid & 63;
    const int quad = lane >> 4, l16 = lane & 15;
    const int e = blockIdx.x >> 2, c0 = (blockIdx.x & 3) * 16;

    // resident b-frags: slots {i:0,1  f:2,3  g:4,5}; tile = (slot>>1)*16 + 2w + (slot&1)
    f16x8 bres[6][8];
    #pragma unroll
    for (int s6 = 0; s6 < 6; ++s6) {
        const int tile = (s6 >> 1)*16 + 2*w + (s6 & 1);
        #pragma unroll
        for (int kc = 0; kc < 8; ++kc)
            bres[s6][kc] = *(const f16x8*)(Whh + (tile*16 + l16)*256 + kc*32 + quad*8);
    }
    {   // stage o-gate rows into LDS (coalesced, once)
        const int r = tid >> 1, hh = tid & 1;
        const f16* src = Whh + (768 + r)*256 + hh*128;
        f16* dst = wl + r*LSTR + hh*128;
        #pragma unroll
        for (int j = 0; j < 16; ++j)
            *(f16x8*)(dst + j*8) = *(const f16x8*)(src + j*8);
    }
    for (int i = tid; i < 2*16*LSTR; i += 512) hb[i] = (f16)0.f;   // h(-1)=0

    // incremental xg pointers, one per r (chain): layout [chain][s][ti][col][g]
    const f16* xp[4];
    #pragma unroll
    for (int r = 0; r < 4; ++r)
        xp[r] = xg + (long)(e*64 + c0 + quad*4 + r)*131072 + (2*w)*64 + l16*4;

    float c[8]    = {0,0,0,0,0,0,0,0};
    float oacc[8] = {0,0,0,0,0,0,0,0};
    __syncthreads();

    #pragma unroll 1
    for (int s = 0; s < 128; ++s) {
        const int rb = s & 1, wb = rb ^ 1;
        // layer-0 history write: h(s-1) from the (stable) read buffer; store-ack
        // latency is covered by this step's compute before the end barrier.
        if (LAYER == 0 && s > 0) {
            const int cc = tid >> 5, kk = (tid & 31) * 8;
            f16x8 hv = *(const f16x8*)(hb + (rb*16 + cc)*LSTR + kk);
            *(f16x8*)(hs0 + ((long)(e*64 + c0 + cc)*128 + (s-1))*256 + kk) = hv;
        }
        // gate preacts for this step: one f16x4 (i,f,g,o) per (q,r), coalesced
        f16x4 xv[2][4];
        #pragma unroll
        for (int r = 0; r < 4; ++r) {
            xv[0][r] = *(const f16x4*)(xp[r]);
            xv[1][r] = *(const f16x4*)(xp[r] + 64);
        }
        #pragma unroll
        for (int q = 0; q < 2; ++q) {
            const int ti = 2*w + q;                     // h-col block
            f32x4 ai = {}, af = {}, ag = {}, ao = {};
            #pragma unroll
            for (int kc = 0; kc < 8; ++kc) {
                f16x8 a  = *(const f16x8*)(hb + (rb*16 + l16)*LSTR + kc*32 + quad*8);
                f16x8 bo = *(const f16x8*)(wl + (ti*16 + l16)*LSTR + kc*32 + quad*8);
                ai = MFMA(a, bres[q][kc],   ai);
                af = MFMA(a, bres[2+q][kc], af);
                ag = MFMA(a, bres[4+q][kc], ag);
                ao = MFMA(a, bo,            ao);
            }
            #pragma unroll
            for (int r = 0; r < 4; ++r) {
                float gi = sigf(ai[r] + (float)xv[q][r][0]);
                float gf = sigf(af[r] + (float)xv[q][r][1]);
                float gg = tanhf_(ag[r] + (float)xv[q][r][2]);
                float go = sigf(ao[r] + (float)xv[q][r][3]);
                const int ci = q*4 + r;
                float cn = gf*c[ci] + gi*gg;
                c[ci] = cn;
                float hn = go * tanhf_(cn);
                if (LAYER == 1) oacc[ci] += hn;
                hb[(wb*16 + quad*4 + r)*LSTR + ti*16 + l16] = (f16)hn;
            }
        }
        #pragma unroll
        for (int r = 0; r < 4; ++r) xp[r] += 1024;
        __syncthreads();
    }
    if (LAYER == 0) {       // final history entry h(127): buffer rb(128)=0
        const int cc = tid >> 5, kk = (tid & 31) * 8;
        f16x8 hv = *(const f16x8*)(hb + (0*16 + cc)*LSTR + kk);
        *(f16x8*)(hs0 + ((long)(e*64 + c0 + cc)*128 + 127)*256 + kk) = hv;
    }
    if (LAYER == 1) {       // time-summed hidden state -> encoder output
        #pragma unroll
        for (int q = 0; q < 2; ++q)
            #pragma unroll
            for (int r = 0; r < 4; ++r)
                out_enc[(long)(e*64 + c0 + quad*4 + r)*256 + (2*w+q)*16 + l16] = oacc[q*4 + r];
    }
}

// ----------------------------------------------------- fp32 FC (head) -------
// Block: [64 rows x 32 cols]; W staged in LDS (broadcast reads), A staged transposed.
// MODE 0: gelu (A = concat(enc0,enc1)); MODE 1: res + relu; MODE 2: relu (scores).
template<int K, int MODE>
__global__ __launch_bounds__(256)
void k_fc(const float* __restrict__ A, const float* __restrict__ W,
          const float* __restrict__ bias, const float* __restrict__ res,
          float* __restrict__ out, const int Nst)
{
    __shared__ float ws[32*64];
    __shared__ float as[64*64];   // [k][m] -> conflict-free compute reads
    const int tid = threadIdx.x;
    const int n0 = blockIdx.x * 32;
    const int m2 = tid & 31, ndg = tid >> 5;
    float acc[2][4] = {};
    for (int kc = 0; kc < K/64; ++kc) {
        __syncthreads();
        {   // stage W [32 cols][64 k]
            const int col = tid >> 3, k8 = (tid & 7)*8;
            const float* src = W + (long)(n0 + col)*K + kc*64 + k8;
            *(float4*)(ws + col*64 + k8)     = *(const float4*)(src);
            *(float4*)(ws + col*64 + k8 + 4) = *(const float4*)(src + 4);
        }
        {   // stage A transposed: as[k][m]
            const int m = tid >> 2, j4 = (tid & 3)*16;
            #pragma unroll
            for (int i4 = 0; i4 < 4; ++i4) {
                const int kk = kc*64 + j4 + i4*4;
                const float* srcA;
                if (MODE == 0) srcA = (kk < 256) ? (A + (long)m*256 + kk)
                                                 : (A + 16384 + (long)m*256 + kk - 256);
                else           srcA = A + (long)m*K + kk;
                float4 v = *(const float4*)srcA;
                as[(j4 + i4*4 + 0)*64 + m] = v.x;
                as[(j4 + i4*4 + 1)*64 + m] = v.y;
                as[(j4 + i4*4 + 2)*64 + m] = v.z;
                as[(j4 + i4*4 + 3)*64 + m] = v.w;
            }
        }
        __syncthreads();
        #pragma unroll 4
        for (int k4 = 0; k4 < 64; k4 += 4) {
            float a0[4], a1[4];
            #pragma unroll
            for (int i = 0; i < 4; ++i) {
                a0[i] = as[(k4+i)*64 + m2];
                a1[i] = as[(k4+i)*64 + m2 + 32];
            }
            #pragma unroll
            for (int j = 0; j < 4; ++j) {
                const float4 wv = *(const float4*)(ws + (ndg*4 + j)*64 + k4);
                acc[0][j] += a0[0]*wv.x + a0[1]*wv.y + a0[2]*wv.z + a0[3]*wv.w;
                acc[1][j] += a1[0]*wv.x + a1[1]*wv.y + a1[2]*wv.z + a1[3]*wv.w;
            }
        }
    }
    #pragma unroll
    for (int i = 0; i < 2; ++i) {
        const int m = m2 + i*32;
        #pragma unroll
        for (int j = 0; j < 4; ++j) {
            const int nn = n0 + ndg*4 + j;
            float v = acc[i][j] + bias[nn];
            if (MODE == 0)      v = 0.5f * v * (1.0f + erff(v * 0.7071067811865475f));
            else if (MODE == 1) v = res[(long)m*1024 + nn] + fmaxf(v, 0.f);
            else                v = fmaxf(v, 0.f);
            out[(long)m*Nst + nn] = v;
        }
    }
}

// ---------------------------------------------------------- batchnorm -------
__global__ void k_bn(const float* __restrict__ h2, const float* __restrict__ g,
                     const float* __restrict__ b, float* __restrict__ h3)
{
    const int col = blockIdx.x*256 + threadIdx.x;     // 4 blocks x 256 = 1024 cols
    float s = 0.f, ss = 0.f;
    for (int m = 0; m < 64; ++m) { float v = h2[m*1024 + col]; s += v; ss += v*v; }
    const float mu  = s * (1.f/64.f);
    const float var = ss * (1.f/64.f) - mu*mu;
    const float rs  = rsqrtf(var + 1e-5f);
    const float gg = g[col], bb = b[col];
    for (int m = 0; m < 64; ++m) {
        float v = h2[m*1024 + col];
        h3[m*1024 + col] = (v - mu)*rs*gg + bb;
    }
}

// ---------------------------------------------------------- count -----------
__global__ void k_count(const float* __restrict__ scores, float* __restrict__ outc)
{
    const int row = blockIdx.x, tid = threadIdx.x;
    const float* p = scores + (long)row*32000;
    int cnt = 0;
    for (int i = tid; i < 32000; i += 256)
        cnt += ((double)p[i] > 0.6400000000000001) ? 1 : 0;   // match np f64 threshold
    __shared__ int red[256];
    red[tid] = cnt; __syncthreads();
    for (int off = 128; off > 0; off >>= 1) {
        if (tid < off) red[tid] += red[tid + off];
        __syncthreads();
    }
    if (tid == 0) outc[row] = (float)(red[0] < 1 ? 1 : red[0]);
}

// ---------------------------------------------------------- launch ----------
extern "C" void kernel_launch(void* const* d_in, const int* in_sizes, int n_in,
                              void* d_out, int out_size, void* d_ws, size_t ws_size,
                              hipStream_t stream)
{
    const float* x1    = (const float*)d_in[0];
    const float* x2    = (const float*)d_in[1];
    const float* Wih0  = (const float*)d_in[2];
    const float* Whh0  = (const float*)d_in[3];
    const float* bih0  = (const float*)d_in[4];
    const float* bhh0  = (const float*)d_in[5];
    const float* Wih1  = (const float*)d_in[6];
    const float* Whh1  = (const float*)d_in[7];
    const float* bih1  = (const float*)d_in[8];
    const float* bhh1  = (const float*)d_in[9];
    const float* fc1_w = (const float*)d_in[10];
    const float* fc1_b = (const float*)d_in[11];
    const float* fc2_w = (const float*)d_in[12];
    const float* fc2_b = (const float*)d_in[13];
    const float* fc3_w = (const float*)d_in[14];
    const float* fc3_b = (const float*)d_in[15];
    const float* bn_g  = (const float*)d_in[16];
    const float* bn_b  = (const float*)d_in[17];
    float* out = (float*)d_out;

    char* ws = (char*)d_ws;
    f16*   x16  = (f16*)(ws);               // [2][64][128][64] f16         (2 MB)
    f16*   w16  = (f16*)(ws + 2097152);     // Wih0 | Whh0 | Wih1 | Whh1 (f16)
    float* bsum = (float*)(ws + 3801088);   // bih0+bhh0 | bih1+bhh1
    f16*   hs0  = (f16*)(ws + 3809280);     // [2][64][128][256] f16        (8 MB)
    f16*   xg   = (f16*)(ws + 12197888);    // [2][64][128][1024] f16 gate-interleaved (32 MB)
    float* enc  = (float*)(ws + 45752320);  // [2][64][256] f32
    float* h1   = (float*)(ws + 45883392);  // [64][1024]
    float* h2   = (float*)(ws + 46145536);
    float* h3   = (float*)(ws + 46407680);  // ends 46,669,824

    k_convert<<<2048, 256, 0, stream>>>(x1,x2,Wih0,Whh0,bih0,bhh0,Wih1,Whh1,bih1,bhh1,
                                        x16, w16, bsum);
    // xg0 = x @ Wih0^T + (bih0+bhh0)  -> f16 gate-interleaved
    k_proj<64><<<dim3(128,8), 512, 0, stream>>>(x16, w16, bsum, xg);
    // layer-0 recurrence, writes hs0 (f16)
    k_lstm<0><<<8, 512, 0, stream>>>(w16 + 65536, xg, hs0, nullptr);
    // xg1 = hs0 @ Wih1^T + (bih1+bhh1)  (reuses xg buffer)
    k_proj<256><<<dim3(128,8), 512, 0, stream>>>(hs0, w16 + 327680, bsum + 1024, xg);
    // layer-1 recurrence + time-sum -> enc
    k_lstm<1><<<8, 512, 0, stream>>>(w16 + 589824, xg, nullptr, enc);
    // head
    k_fc<512,0><<<32, 256, 0, stream>>>(enc, fc1_w, fc1_b, nullptr, h1, 1024);
    k_fc<1024,1><<<32, 256, 0, stream>>>(h1, fc2_w, fc2_b, h1, h2, 1024);
    k_bn<<<4, 256, 0, stream>>>(h2, bn_g, bn_b, h3);
    k_fc<1024,2><<<1000, 256, 0, stream>>>(h3, fc3_w, fc3_b, nullptr, out, 32000);
    k_count<<<64, 256, 0, stream>>>(out, out + 2048000);
}

// Round 3
// 1036.177 us; speedup vs baseline: 1.8634x; 1.1892x over previous
//
#include <hip/hip_runtime.h>
#include <cmath>

// ConceptLearner LSTM on MI355X.
// Sizes: B=64, S=128, D=64, H=256 (4H=1024 gates), P=1024, V*R=32000.
// R3: layer0 / xg1-projection / layer1 run CONCURRENTLY as a 24-block pipelined
// mega-kernel (8 L0 + 8 PROJ + 8 L1 blocks, one per chain-group), synced with
// agent-scope release/acquire flags. Saves the serial lstm1+proj time (~440us).

typedef _Float16 f16;
typedef _Float16 f16x8 __attribute__((ext_vector_type(8)));
typedef _Float16 f16x4 __attribute__((ext_vector_type(4)));
typedef float f32x4 __attribute__((ext_vector_type(4)));

#define MFMA(a,b,c) __builtin_amdgcn_mfma_f32_16x16x32_f16((a),(b),(c),0,0,0)
#define LSTR 280   // LDS row stride in f16

__device__ __forceinline__ float frcp(float x) { return __builtin_amdgcn_rcpf(x); }
__device__ __forceinline__ float sigf(float x)  { return frcp(1.f + __expf(-x)); }
__device__ __forceinline__ float tanhf_(float x){ return 1.f - 2.f*frcp(__expf(2.f*x) + 1.f); }

// ---------------------------------------------------------------- convert ---
__global__ void k_convert(const float* __restrict__ x1, const float* __restrict__ x2,
                          const float* __restrict__ Wih0, const float* __restrict__ Whh0,
                          const float* __restrict__ bih0, const float* __restrict__ bhh0,
                          const float* __restrict__ Wih1, const float* __restrict__ Whh1,
                          const float* __restrict__ bih1, const float* __restrict__ bhh1,
                          f16* __restrict__ x16, f16* __restrict__ w16, float* __restrict__ bsum,
                          int* __restrict__ flg)
{
    int i = blockIdx.x * 256 + threadIdx.x;           // grid 2048*256
    if (i < 524288) { x16[i] = (f16)x1[i]; x16[524288 + i] = (f16)x2[i]; }
    if (i < 65536)  w16[i] = (f16)Wih0[i];            // Wih0 [1024][64]
    if (i < 262144) {
        w16[65536  + i] = (f16)Whh0[i];               // Whh0 [1024][256]
        w16[327680 + i] = (f16)Wih1[i];               // Wih1 [1024][256]
        w16[589824 + i] = (f16)Whh1[i];               // Whh1 [1024][256]
    }
    if (i < 1024) { bsum[i] = bih0[i] + bhh0[i]; bsum[1024 + i] = bih1[i] + bhh1[i]; }
    if (i < 64) flg[i] = 0;                           // pipeline flags
}

// ------------------------------------------------- input projection (MFMA) --
// out preacts stored f16, gate-interleaved: row offset = ti*64 + col*4 + gate.
template<int K>
__global__ __launch_bounds__(512)
void k_proj(const f16* __restrict__ A, const f16* __restrict__ Bw,
            const float* __restrict__ bias, f16* __restrict__ out)
{
    const int w = threadIdx.x >> 6, lane = threadIdx.x & 63;
    const int quad = lane >> 4, l16 = lane & 15;
    const long m0 = (long)blockIdx.x * 128 + w * 16;   // wave's M-tile
    f32x4 acc[2][4] = {};
    #pragma unroll
    for (int kc = 0; kc < K/32; ++kc) {
        const int ko = kc*32 + quad*8;
        f16x8 a = *(const f16x8*)(A + (m0 + l16)*K + ko);           // A[m=lane&15][k]
        #pragma unroll
        for (int tg = 0; tg < 2; ++tg) {
            const int ti = blockIdx.y*2 + tg;
            #pragma unroll
            for (int g = 0; g < 4; ++g) {
                f16x8 b = *(const f16x8*)(Bw + (long)(g*256 + ti*16 + l16)*K + ko);
                acc[tg][g] = MFMA(a, b, acc[tg][g]);
            }
        }
    }
    #pragma unroll
    for (int tg = 0; tg < 2; ++tg) {
        const int ti = blockIdx.y*2 + tg;
        float bi[4];
        #pragma unroll
        for (int g = 0; g < 4; ++g) bi[g] = bias[g*256 + ti*16 + l16];
        #pragma unroll
        for (int r = 0; r < 4; ++r) {                  // D: row=quad*4+r, col=lane&15
            long mm = m0 + quad*4 + r;
            f16x4 pv;
            #pragma unroll
            for (int g = 0; g < 4; ++g) pv[g] = (f16)(acc[tg][g][r] + bi[g]);
            *(f16x4*)(out + mm*1024 + ti*64 + l16*4) = pv;
        }
    }
}

// --------------------------------------------- pipelined LSTM mega-kernel ---
// 24 blocks x 512 thr. role = blockIdx>>3: 0=layer0, 1=xg1 projection, 2=layer1.
// g = blockIdx&7 selects the 16-chain group (global chains g*16..g*16+15).
// flags[g]    : h0 progress  (value s => h0(0..s-1) ready, 128 = all)
// flags[8+g]  : xg1 progress (value s => xg1(0..s-1) ready)
// h0s layout: step-major [s][chain][k] f16. xg1: [chain][s][ti*64+col*4+gate] f16.
__global__ __launch_bounds__(512, 2)
void k_mega(const f16* __restrict__ w16, const f16* __restrict__ xg0,
            f16* __restrict__ xg1, f16* __restrict__ h0s,
            const float* __restrict__ bsum1, float* __restrict__ out_enc,
            int* __restrict__ flags)
{
    __shared__ f16 wl[256*LSTR];    // o-gate rows 768..1023 of this role's W
    __shared__ f16 hb[2*16*LSTR];   // double-buffered h (lstm roles only)
    const int tid = threadIdx.x;
    const int w = tid >> 6, lane = tid & 63;
    const int quad = lane >> 4, l16 = lane & 15;
    const int role = blockIdx.x >> 3, g = blockIdx.x & 7;

    const f16* W = (role == 0) ? w16 + 65536           // Whh0
                 : (role == 1) ? w16 + 327680          // Wih1
                               : w16 + 589824;         // Whh1

    // resident b-frags: slots {i:0,1  f:2,3  g:4,5}; tile = (slot>>1)*16 + 2w + (slot&1)
    f16x8 bres[6][8];
    #pragma unroll
    for (int s6 = 0; s6 < 6; ++s6) {
        const int tile = (s6 >> 1)*16 + 2*w + (s6 & 1);
        #pragma unroll
        for (int kc = 0; kc < 8; ++kc)
            bres[s6][kc] = *(const f16x8*)(W + (tile*16 + l16)*256 + kc*32 + quad*8);
    }
    {   // stage o-gate rows into LDS (coalesced, once)
        const int r = tid >> 1, hh = tid & 1;
        const f16* src = W + (768 + r)*256 + hh*128;
        f16* dst = wl + r*LSTR + hh*128;
        #pragma unroll
        for (int j = 0; j < 16; ++j)
            *(f16x8*)(dst + j*8) = *(const f16x8*)(src + j*8);
    }

    if (role == 1) {    // ---------------- projection stage: xg1(s) = h0(s)@Wih1^T + b
        float bi[2][4];
        #pragma unroll
        for (int q = 0; q < 2; ++q)
            #pragma unroll
            for (int g4 = 0; g4 < 4; ++g4) bi[q][g4] = bsum1[g4*256 + (2*w+q)*16 + l16];
        __syncthreads();
        #pragma unroll 1
        for (int s = 0; s < 128; ++s) {
            if (tid == 0) {
                while (__hip_atomic_load(&flags[g], __ATOMIC_ACQUIRE,
                                         __HIP_MEMORY_SCOPE_AGENT) < s + 1)
                    __builtin_amdgcn_s_sleep(2);
            }
            __syncthreads();
            const f16* hrow = h0s + ((long)s*128 + g*16 + l16)*256 + quad*8;
            f16x8 av[8];
            #pragma unroll
            for (int kc = 0; kc < 8; ++kc) av[kc] = *(const f16x8*)(hrow + kc*32);
            #pragma unroll
            for (int q = 0; q < 2; ++q) {
                const int ti = 2*w + q;
                f32x4 ai = {}, af = {}, ag = {}, ao = {};
                #pragma unroll
                for (int kc = 0; kc < 8; ++kc) {
                    f16x8 bo = *(const f16x8*)(wl + (ti*16 + l16)*LSTR + kc*32 + quad*8);
                    ai = MFMA(av[kc], bres[q][kc],   ai);
                    af = MFMA(av[kc], bres[2+q][kc], af);
                    ag = MFMA(av[kc], bres[4+q][kc], ag);
                    ao = MFMA(av[kc], bo,            ao);
                }
                #pragma unroll
                for (int r = 0; r < 4; ++r) {
                    f16x4 pv;
                    pv[0] = (f16)(ai[r] + bi[q][0]);
                    pv[1] = (f16)(af[r] + bi[q][1]);
                    pv[2] = (f16)(ag[r] + bi[q][2]);
                    pv[3] = (f16)(ao[r] + bi[q][3]);
                    *(f16x4*)(xg1 + ((long)(g*16 + quad*4 + r)*128 + s)*1024
                                  + ti*64 + l16*4) = pv;
                }
            }
            __syncthreads();   // barrier drains all stores (vmcnt(0) before s_barrier)
            if (tid == 0)
                __hip_atomic_store(&flags[8+g], s + 1, __ATOMIC_RELEASE,
                                   __HIP_MEMORY_SCOPE_AGENT);
        }
        return;
    }

    // ---------------- LSTM stages (role 0 = layer0, role 2 = layer1) ----------
    for (int i = tid; i < 2*16*LSTR; i += 512) hb[i] = (f16)0.f;   // h(-1)=0

    const f16* xg = (role == 0) ? xg0 : xg1;
    const f16* xp[4];
    #pragma unroll
    for (int r = 0; r < 4; ++r)
        xp[r] = xg + (long)(g*16 + quad*4 + r)*131072 + (2*w)*64 + l16*4;

    float c[8]    = {0,0,0,0,0,0,0,0};
    float oacc[8] = {0,0,0,0,0,0,0,0};
    __syncthreads();

    #pragma unroll 1
    for (int s = 0; s < 128; ++s) {
        const int rb = s & 1, wb = rb ^ 1;
        if (role == 2) {       // wait for xg1(s)
            if (tid == 0) {
                while (__hip_atomic_load(&flags[8+g], __ATOMIC_ACQUIRE,
                                         __HIP_MEMORY_SCOPE_AGENT) < s + 1)
                    __builtin_amdgcn_s_sleep(2);
            }
            __syncthreads();
        }
        if (role == 0 && s > 0) {   // h(s-1) -> global (step-major), off critical path
            const int cc = tid >> 5, kk = (tid & 31) * 8;
            f16x8 hv = *(const f16x8*)(hb + (rb*16 + cc)*LSTR + kk);
            *(f16x8*)(h0s + ((long)(s-1)*128 + g*16 + cc)*256 + kk) = hv;
        }
        f16x4 xv[2][4];
        #pragma unroll
        for (int r = 0; r < 4; ++r) {
            xv[0][r] = *(const f16x4*)(xp[r]);
            xv[1][r] = *(const f16x4*)(xp[r] + 64);
        }
        #pragma unroll
        for (int q = 0; q < 2; ++q) {
            const int ti = 2*w + q;
            f32x4 ai = {}, af = {}, ag = {}, ao = {};
            #pragma unroll
            for (int kc = 0; kc < 8; ++kc) {
                f16x8 a  = *(const f16x8*)(hb + (rb*16 + l16)*LSTR + kc*32 + quad*8);
                f16x8 bo = *(const f16x8*)(wl + (ti*16 + l16)*LSTR + kc*32 + quad*8);
                ai = MFMA(a, bres[q][kc],   ai);
                af = MFMA(a, bres[2+q][kc], af);
                ag = MFMA(a, bres[4+q][kc], ag);
                ao = MFMA(a, bo,            ao);
            }
            #pragma unroll
            for (int r = 0; r < 4; ++r) {
                float gi = sigf(ai[r] + (float)xv[q][r][0]);
                float gf = sigf(af[r] + (float)xv[q][r][1]);
                float gg = tanhf_(ag[r] + (float)xv[q][r][2]);
                float go = sigf(ao[r] + (float)xv[q][r][3]);
                const int ci = q*4 + r;
                float cn = gf*c[ci] + gi*gg;
                c[ci] = cn;
                float hn = go * tanhf_(cn);
                if (role == 2) oacc[ci] += hn;
                hb[(wb*16 + quad*4 + r)*LSTR + ti*16 + l16] = (f16)hn;
            }
        }
        #pragma unroll
        for (int r = 0; r < 4; ++r) xp[r] += 1024;
        __syncthreads();           // also drains the h(s-1) global store (vmcnt)
        if (role == 0 && tid == 0)
            __hip_atomic_store(&flags[g], s, __ATOMIC_RELEASE,
                               __HIP_MEMORY_SCOPE_AGENT);
    }
    if (role == 0) {       // final history entry h(127): buffer rb(128)=0
        const int cc = tid >> 5, kk = (tid & 31) * 8;
        f16x8 hv = *(const f16x8*)(hb + (0*16 + cc)*LSTR + kk);
        *(f16x8*)(h0s + ((long)127*128 + g*16 + cc)*256 + kk) = hv;
        __syncthreads();
        if (tid == 0)
            __hip_atomic_store(&flags[g], 128, __ATOMIC_RELEASE,
                               __HIP_MEMORY_SCOPE_AGENT);
    }
    if (role == 2) {       // time-summed hidden state -> encoder output
        #pragma unroll
        for (int q = 0; q < 2; ++q)
            #pragma unroll
            for (int r = 0; r < 4; ++r)
                out_enc[(long)(g*16 + quad*4 + r)*256 + (2*w+q)*16 + l16] = oacc[q*4 + r];
    }
}

// ----------------------------------------------------- fp32 FC (head) -------
template<int K, int MODE>
__global__ __launch_bounds__(256)
void k_fc(const float* __restrict__ A, const float* __restrict__ W,
          const float* __restrict__ bias, const float* __restrict__ res,
          float* __restrict__ out, const int Nst)
{
    __shared__ float ws[32*64];
    __shared__ float as[64*64];   // [k][m]
    const int tid = threadIdx.x;
    const int n0 = blockIdx.x * 32;
    const int m2 = tid & 31, ndg = tid >> 5;
    float acc[2][4] = {};
    for (int kc = 0; kc < K/64; ++kc) {
        __syncthreads();
        {   // stage W [32 cols][64 k]
            const int col = tid >> 3, k8 = (tid & 7)*8;
            const float* src = W + (long)(n0 + col)*K + kc*64 + k8;
            *(float4*)(ws + col*64 + k8)     = *(const float4*)(src);
            *(float4*)(ws + col*64 + k8 + 4) = *(const float4*)(src + 4);
        }
        {   // stage A transposed: as[k][m]
            const int m = tid >> 2, j4 = (tid & 3)*16;
            #pragma unroll
            for (int i4 = 0; i4 < 4; ++i4) {
                const int kk = kc*64 + j4 + i4*4;
                const float* srcA;
                if (MODE == 0) srcA = (kk < 256) ? (A + (long)m*256 + kk)
                                                 : (A + 16384 + (long)m*256 + kk - 256);
                else           srcA = A + (long)m*K + kk;
                float4 v = *(const float4*)srcA;
                as[(j4 + i4*4 + 0)*64 + m] = v.x;
                as[(j4 + i4*4 + 1)*64 + m] = v.y;
                as[(j4 + i4*4 + 2)*64 + m] = v.z;
                as[(j4 + i4*4 + 3)*64 + m] = v.w;
            }
        }
        __syncthreads();
        #pragma unroll 4
        for (int k4 = 0; k4 < 64; k4 += 4) {
            float a0[4], a1[4];
            #pragma unroll
            for (int i = 0; i < 4; ++i) {
                a0[i] = as[(k4+i)*64 + m2];
                a1[i] = as[(k4+i)*64 + m2 + 32];
            }
            #pragma unroll
            for (int j = 0; j < 4; ++j) {
                const float4 wv = *(const float4*)(ws + (ndg*4 + j)*64 + k4);
                acc[0][j] += a0[0]*wv.x + a0[1]*wv.y + a0[2]*wv.z + a0[3]*wv.w;
                acc[1][j] += a1[0]*wv.x + a1[1]*wv.y + a1[2]*wv.z + a1[3]*wv.w;
            }
        }
    }
    #pragma unroll
    for (int i = 0; i < 2; ++i) {
        const int m = m2 + i*32;
        #pragma unroll
        for (int j = 0; j < 4; ++j) {
            const int nn = n0 + ndg*4 + j;
            float v = acc[i][j] + bias[nn];
            if (MODE == 0)      v = 0.5f * v * (1.0f + erff(v * 0.7071067811865475f));
            else if (MODE == 1) v = res[(long)m*1024 + nn] + fmaxf(v, 0.f);
            else                v = fmaxf(v, 0.f);
            out[(long)m*Nst + nn] = v;
        }
    }
}

// ---------------------------------------------------------- batchnorm -------
__global__ void k_bn(const float* __restrict__ h2, const float* __restrict__ g,
                     const float* __restrict__ b, float* __restrict__ h3)
{
    const int col = blockIdx.x*256 + threadIdx.x;
    float s = 0.f, ss = 0.f;
    for (int m = 0; m < 64; ++m) { float v = h2[m*1024 + col]; s += v; ss += v*v; }
    const float mu  = s * (1.f/64.f);
    const float var = ss * (1.f/64.f) - mu*mu;
    const float rs  = rsqrtf(var + 1e-5f);
    const float gg = g[col], bb = b[col];
    for (int m = 0; m < 64; ++m) {
        float v = h2[m*1024 + col];
        h3[m*1024 + col] = (v - mu)*rs*gg + bb;
    }
}

// ---------------------------------------------------------- count -----------
__global__ void k_count(const float* __restrict__ scores, float* __restrict__ outc)
{
    const int row = blockIdx.x, tid = threadIdx.x;
    const float* p = scores + (long)row*32000;
    int cnt = 0;
    for (int i = tid; i < 32000; i += 256)
        cnt += ((double)p[i] > 0.6400000000000001) ? 1 : 0;
    __shared__ int red[256];
    red[tid] = cnt; __syncthreads();
    for (int off = 128; off > 0; off >>= 1) {
        if (tid < off) red[tid] += red[tid + off];
        __syncthreads();
    }
    if (tid == 0) outc[row] = (float)(red[0] < 1 ? 1 : red[0]);
}

// ---------------------------------------------------------- launch ----------
extern "C" void kernel_launch(void* const* d_in, const int* in_sizes, int n_in,
                              void* d_out, int out_size, void* d_ws, size_t ws_size,
                              hipStream_t stream)
{
    const float* x1    = (const float*)d_in[0];
    const float* x2    = (const float*)d_in[1];
    const float* Wih0  = (const float*)d_in[2];
    const float* Whh0  = (const float*)d_in[3];
    const float* bih0  = (const float*)d_in[4];
    const float* bhh0  = (const float*)d_in[5];
    const float* Wih1  = (const float*)d_in[6];
    const float* Whh1  = (const float*)d_in[7];
    const float* bih1  = (const float*)d_in[8];
    const float* bhh1  = (const float*)d_in[9];
    const float* fc1_w = (const float*)d_in[10];
    const float* fc1_b = (const float*)d_in[11];
    const float* fc2_w = (const float*)d_in[12];
    const float* fc2_b = (const float*)d_in[13];
    const float* fc3_w = (const float*)d_in[14];
    const float* fc3_b = (const float*)d_in[15];
    const float* bn_g  = (const float*)d_in[16];
    const float* bn_b  = (const float*)d_in[17];
    float* out = (float*)d_out;

    char* ws = (char*)d_ws;
    f16*   x16   = (f16*)(ws);                // 2,097,152 B
    f16*   w16   = (f16*)(ws + 2097152);      // 1,703,936 B
    float* bsum  = (float*)(ws + 3801088);    // 8,192 B
    int*   flags = (int*)(ws + 3809280);      // 256 B
    float* enc   = (float*)(ws + 3809536);    // 131,072 B  [2][64][256]
    f16*   h0s   = (f16*)(ws + 3940608);      // 8,388,608 B  [128][128][256] step-major
    f16*   xg0   = (f16*)(ws + 12329216);     // 33,554,432 B [128 chains][128][1024]
    f16*   xg1   = (f16*)(ws + 45883648);     // 33,554,432 B (ends 79,438,080)
    float* h1    = (float*)(ws + 12329216);   // overlay xg0 region (dead after mega)
    float* h2    = (float*)(ws + 12591360);
    float* h3    = (float*)(ws + 12853504);

    k_convert<<<2048, 256, 0, stream>>>(x1,x2,Wih0,Whh0,bih0,bhh0,Wih1,Whh1,bih1,bhh1,
                                        x16, w16, bsum, flags);
    // xg0 = x @ Wih0^T + (bih0+bhh0)  -> f16 gate-interleaved
    k_proj<64><<<dim3(128,8), 512, 0, stream>>>(x16, w16, bsum, xg0);
    // pipelined layer0 | xg1-projection | layer1
    k_mega<<<24, 512, 0, stream>>>(w16, xg0, xg1, h0s, bsum + 1024, enc, flags);
    // head
    k_fc<512,0><<<32, 256, 0, stream>>>(enc, fc1_w, fc1_b, nullptr, h1, 1024);
    k_fc<1024,1><<<32, 256, 0, stream>>>(h1, fc2_w, fc2_b, h1, h2, 1024);
    k_bn<<<4, 256, 0, stream>>>(h2, bn_g, bn_b, h3);
    k_fc<1024,2><<<1000, 256, 0, stream>>>(h3, fc3_w, fc3_b, nullptr, out, 32000);
    k_count<<<64, 256, 0, stream>>>(out, out + 2048000);
}

// Round 4
// 987.375 us; speedup vs baseline: 1.9555x; 1.0494x over previous
//
#include <hip/hip_runtime.h>
#include <cmath>

// ConceptLearner LSTM on MI355X.
// Sizes: B=64, S=128, D=64, H=256 (4H=1024 gates), P=1024, V*R=32000.
// R4: pipeline sync coarsened to 2-step chunks with relaxed-spin polling
// (acquire-confirm once per chunk; no per-poll buffer_inv), BN fused into fc2.

typedef _Float16 f16;
typedef _Float16 f16x8 __attribute__((ext_vector_type(8)));
typedef _Float16 f16x4 __attribute__((ext_vector_type(4)));
typedef float f32x4 __attribute__((ext_vector_type(4)));

#define MFMA(a,b,c) __builtin_amdgcn_mfma_f32_16x16x32_f16((a),(b),(c),0,0,0)
#define LSTR 280   // LDS row stride in f16

__device__ __forceinline__ float frcp(float x) { return __builtin_amdgcn_rcpf(x); }
__device__ __forceinline__ float sigf(float x)  { return frcp(1.f + __expf(-x)); }
__device__ __forceinline__ float tanhf_(float x){ return 1.f - 2.f*frcp(__expf(2.f*x) + 1.f); }

// Relaxed spin until flag >= target, then one acquire load (inv) to fence data.
__device__ __forceinline__ void wait_flag(int* f, int target) {
    while (__hip_atomic_load(f, __ATOMIC_RELAXED, __HIP_MEMORY_SCOPE_AGENT) < target)
        __builtin_amdgcn_s_sleep(1);
    (void)__hip_atomic_load(f, __ATOMIC_ACQUIRE, __HIP_MEMORY_SCOPE_AGENT);
}

// ---------------------------------------------------------------- convert ---
__global__ void k_convert(const float* __restrict__ x1, const float* __restrict__ x2,
                          const float* __restrict__ Wih0, const float* __restrict__ Whh0,
                          const float* __restrict__ bih0, const float* __restrict__ bhh0,
                          const float* __restrict__ Wih1, const float* __restrict__ Whh1,
                          const float* __restrict__ bih1, const float* __restrict__ bhh1,
                          f16* __restrict__ x16, f16* __restrict__ w16, float* __restrict__ bsum,
                          int* __restrict__ flg)
{
    int i = blockIdx.x * 256 + threadIdx.x;           // grid 2048*256
    if (i < 524288) { x16[i] = (f16)x1[i]; x16[524288 + i] = (f16)x2[i]; }
    if (i < 65536)  w16[i] = (f16)Wih0[i];            // Wih0 [1024][64]
    if (i < 262144) {
        w16[65536  + i] = (f16)Whh0[i];               // Whh0 [1024][256]
        w16[327680 + i] = (f16)Wih1[i];               // Wih1 [1024][256]
        w16[589824 + i] = (f16)Whh1[i];               // Whh1 [1024][256]
    }
    if (i < 1024) { bsum[i] = bih0[i] + bhh0[i]; bsum[1024 + i] = bih1[i] + bhh1[i]; }
    if (i < 64) flg[i] = 0;                           // pipeline flags
}

// ------------------------------------------------- input projection (MFMA) --
// out preacts stored f16, gate-interleaved: row offset = ti*64 + col*4 + gate.
template<int K>
__global__ __launch_bounds__(512)
void k_proj(const f16* __restrict__ A, const f16* __restrict__ Bw,
            const float* __restrict__ bias, f16* __restrict__ out)
{
    const int w = threadIdx.x >> 6, lane = threadIdx.x & 63;
    const int quad = lane >> 4, l16 = lane & 15;
    const long m0 = (long)blockIdx.x * 128 + w * 16;   // wave's M-tile
    f32x4 acc[2][4] = {};
    #pragma unroll
    for (int kc = 0; kc < K/32; ++kc) {
        const int ko = kc*32 + quad*8;
        f16x8 a = *(const f16x8*)(A + (m0 + l16)*K + ko);           // A[m=lane&15][k]
        #pragma unroll
        for (int tg = 0; tg < 2; ++tg) {
            const int ti = blockIdx.y*2 + tg;
            #pragma unroll
            for (int g = 0; g < 4; ++g) {
                f16x8 b = *(const f16x8*)(Bw + (long)(g*256 + ti*16 + l16)*K + ko);
                acc[tg][g] = MFMA(a, b, acc[tg][g]);
            }
        }
    }
    #pragma unroll
    for (int tg = 0; tg < 2; ++tg) {
        const int ti = blockIdx.y*2 + tg;
        float bi[4];
        #pragma unroll
        for (int g = 0; g < 4; ++g) bi[g] = bias[g*256 + ti*16 + l16];
        #pragma unroll
        for (int r = 0; r < 4; ++r) {                  // D: row=quad*4+r, col=lane&15
            long mm = m0 + quad*4 + r;
            f16x4 pv;
            #pragma unroll
            for (int g = 0; g < 4; ++g) pv[g] = (f16)(acc[tg][g][r] + bi[g]);
            *(f16x4*)(out + mm*1024 + ti*64 + l16*4) = pv;
        }
    }
}

// --------------------------------------------- pipelined LSTM mega-kernel ---
// 24 blocks x 512 thr. role = blockIdx>>3: 0=layer0, 1=xg1 projection, 2=layer1.
// g = blockIdx&7 selects the 16-chain group.
// flags[g]   : h0 progress  (value v => h0(0..v-1) ready; released at even steps)
// flags[8+g] : xg1 progress (value v => xg1(0..v-1) ready; released per 2-chunk)
__global__ __launch_bounds__(512, 2)
void k_mega(const f16* __restrict__ w16, const f16* __restrict__ xg0,
            f16* __restrict__ xg1, f16* __restrict__ h0s,
            const float* __restrict__ bsum1, float* __restrict__ out_enc,
            int* __restrict__ flags)
{
    __shared__ f16 wl[256*LSTR];    // o-gate rows 768..1023 of this role's W
    __shared__ f16 hb[2*16*LSTR];   // double-buffered h (lstm roles only)
    const int tid = threadIdx.x;
    const int w = tid >> 6, lane = tid & 63;
    const int quad = lane >> 4, l16 = lane & 15;
    const int role = blockIdx.x >> 3, g = blockIdx.x & 7;

    const f16* W = (role == 0) ? w16 + 65536           // Whh0
                 : (role == 1) ? w16 + 327680          // Wih1
                               : w16 + 589824;         // Whh1

    // resident b-frags: slots {i:0,1  f:2,3  g:4,5}; tile = (slot>>1)*16 + 2w + (slot&1)
    f16x8 bres[6][8];
    #pragma unroll
    for (int s6 = 0; s6 < 6; ++s6) {
        const int tile = (s6 >> 1)*16 + 2*w + (s6 & 1);
        #pragma unroll
        for (int kc = 0; kc < 8; ++kc)
            bres[s6][kc] = *(const f16x8*)(W + (tile*16 + l16)*256 + kc*32 + quad*8);
    }
    {   // stage o-gate rows into LDS (coalesced, once)
        const int r = tid >> 1, hh = tid & 1;
        const f16* src = W + (768 + r)*256 + hh*128;
        f16* dst = wl + r*LSTR + hh*128;
        #pragma unroll
        for (int j = 0; j < 16; ++j)
            *(f16x8*)(dst + j*8) = *(const f16x8*)(src + j*8);
    }

    if (role == 1) {    // ---------------- projection stage: xg1(s) = h0(s)@Wih1^T + b
        float bi[2][4];
        #pragma unroll
        for (int q = 0; q < 2; ++q)
            #pragma unroll
            for (int g4 = 0; g4 < 4; ++g4) bi[q][g4] = bsum1[g4*256 + (2*w+q)*16 + l16];
        __syncthreads();
        #pragma unroll 1
        for (int s = 0; s < 128; ++s) {
            if ((s & 1) == 0) {              // chunk head: wait for h0(s), h0(s+1)
                if (tid == 0) wait_flag(&flags[g], s + 2);
                __syncthreads();
            }
            const f16* hrow = h0s + ((long)s*128 + g*16 + l16)*256 + quad*8;
            f16x8 av[8];
            #pragma unroll
            for (int kc = 0; kc < 8; ++kc) av[kc] = *(const f16x8*)(hrow + kc*32);
            #pragma unroll
            for (int q = 0; q < 2; ++q) {
                const int ti = 2*w + q;
                f32x4 ai = {}, af = {}, ag = {}, ao = {};
                #pragma unroll
                for (int kc = 0; kc < 8; ++kc) {
                    f16x8 bo = *(const f16x8*)(wl + (ti*16 + l16)*LSTR + kc*32 + quad*8);
                    ai = MFMA(av[kc], bres[q][kc],   ai);
                    af = MFMA(av[kc], bres[2+q][kc], af);
                    ag = MFMA(av[kc], bres[4+q][kc], ag);
                    ao = MFMA(av[kc], bo,            ao);
                }
                #pragma unroll
                for (int r = 0; r < 4; ++r) {
                    f16x4 pv;
                    pv[0] = (f16)(ai[r] + bi[q][0]);
                    pv[1] = (f16)(af[r] + bi[q][1]);
                    pv[2] = (f16)(ag[r] + bi[q][2]);
                    pv[3] = (f16)(ao[r] + bi[q][3]);
                    *(f16x4*)(xg1 + ((long)(g*16 + quad*4 + r)*128 + s)*1024
                                  + ti*64 + l16*4) = pv;
                }
            }
            if (s & 1) {                     // chunk tail: drain stores, release
                __syncthreads();             // vmcnt(0) before s_barrier
                if (tid == 0)
                    __hip_atomic_store(&flags[8+g], s + 1, __ATOMIC_RELEASE,
                                       __HIP_MEMORY_SCOPE_AGENT);
            }
        }
        return;
    }

    // ---------------- LSTM stages (role 0 = layer0, role 2 = layer1) ----------
    for (int i = tid; i < 2*16*LSTR; i += 512) hb[i] = (f16)0.f;   // h(-1)=0

    const f16* xg = (role == 0) ? xg0 : xg1;
    const f16* xp[4];
    #pragma unroll
    for (int r = 0; r < 4; ++r)
        xp[r] = xg + (long)(g*16 + quad*4 + r)*131072 + (2*w)*64 + l16*4;

    float c[8]    = {0,0,0,0,0,0,0,0};
    float oacc[8] = {0,0,0,0,0,0,0,0};
    __syncthreads();

    #pragma unroll 1
    for (int s = 0; s < 128; ++s) {
        const int rb = s & 1, wb = rb ^ 1;
        if (role == 2 && (s & 1) == 0) {     // chunk head: wait for xg1(s), xg1(s+1)
            if (tid == 0) wait_flag(&flags[8+g], s + 2);
            __syncthreads();
        }
        if (role == 0 && s > 0) {   // h(s-1) -> global (step-major), off critical path
            const int cc = tid >> 5, kk = (tid & 31) * 8;
            f16x8 hv = *(const f16x8*)(hb + (rb*16 + cc)*LSTR + kk);
            *(f16x8*)(h0s + ((long)(s-1)*128 + g*16 + cc)*256 + kk) = hv;
        }
        f16x4 xv[2][4];
        #pragma unroll
        for (int r = 0; r < 4; ++r) {
            xv[0][r] = *(const f16x4*)(xp[r]);
            xv[1][r] = *(const f16x4*)(xp[r] + 64);
        }
        #pragma unroll
        for (int q = 0; q < 2; ++q) {
            const int ti = 2*w + q;
            f32x4 ai = {}, af = {}, ag = {}, ao = {};
            #pragma unroll
            for (int kc = 0; kc < 8; ++kc) {
                f16x8 a  = *(const f16x8*)(hb + (rb*16 + l16)*LSTR + kc*32 + quad*8);
                f16x8 bo = *(const f16x8*)(wl + (ti*16 + l16)*LSTR + kc*32 + quad*8);
                ai = MFMA(a, bres[q][kc],   ai);
                af = MFMA(a, bres[2+q][kc], af);
                ag = MFMA(a, bres[4+q][kc], ag);
                ao = MFMA(a, bo,            ao);
            }
            #pragma unroll
            for (int r = 0; r < 4; ++r) {
                float gi = sigf(ai[r] + (float)xv[q][r][0]);
                float gf = sigf(af[r] + (float)xv[q][r][1]);
                float gg = tanhf_(ag[r] + (float)xv[q][r][2]);
                float go = sigf(ao[r] + (float)xv[q][r][3]);
                const int ci = q*4 + r;
                float cn = gf*c[ci] + gi*gg;
                c[ci] = cn;
                float hn = go * tanhf_(cn);
                if (role == 2) oacc[ci] += hn;
                hb[(wb*16 + quad*4 + r)*LSTR + ti*16 + l16] = (f16)hn;
            }
        }
        #pragma unroll
        for (int r = 0; r < 4; ++r) xp[r] += 1024;
        __syncthreads();           // drains the h(s-1) global store (vmcnt)
        // release at even steps s>=2: h0(0..s-1) globally visible after wbl2
        if (role == 0 && (s & 1) == 0 && s > 0 && tid == 0)
            __hip_atomic_store(&flags[g], s, __ATOMIC_RELEASE,
                               __HIP_MEMORY_SCOPE_AGENT);
    }
    if (role == 0) {       // final history entry h(127): buffer rb(128)=0
        const int cc = tid >> 5, kk = (tid & 31) * 8;
        f16x8 hv = *(const f16x8*)(hb + (0*16 + cc)*LSTR + kk);
        *(f16x8*)(h0s + ((long)127*128 + g*16 + cc)*256 + kk) = hv;
        __syncthreads();
        if (tid == 0)
            __hip_atomic_store(&flags[g], 128, __ATOMIC_RELEASE,
                               __HIP_MEMORY_SCOPE_AGENT);
    }
    if (role == 2) {       // time-summed hidden state -> encoder output
        #pragma unroll
        for (int q = 0; q < 2; ++q)
            #pragma unroll
            for (int r = 0; r < 4; ++r)
                out_enc[(long)(g*16 + quad*4 + r)*256 + (2*w+q)*16 + l16] = oacc[q*4 + r];
    }
}

// ----------------------------------------------------- fp32 FC (head) -------
// MODE 0: gelu (A = concat(enc0,enc1)); MODE 1: res+relu then fused BatchNorm
// (block owns all 64 rows of its 32 cols -> block-local stats); MODE 2: relu.
template<int K, int MODE>
__global__ __launch_bounds__(256)
void k_fc(const float* __restrict__ A, const float* __restrict__ W,
          const float* __restrict__ bias, const float* __restrict__ res,
          const float* __restrict__ bng, const float* __restrict__ bnb,
          float* __restrict__ out, const int Nst)
{
    __shared__ float ws[32*64];
    __shared__ float as[64*64];   // [k][m]; MODE 1 reuses as stride-33 stats buffer
    __shared__ float mus[32], rss[32];
    const int tid = threadIdx.x;
    const int n0 = blockIdx.x * 32;
    const int m2 = tid & 31, ndg = tid >> 5;
    float acc[2][4] = {};
    for (int kc = 0; kc < K/64; ++kc) {
        __syncthreads();
        {   // stage W [32 cols][64 k]
            const int col = tid >> 3, k8 = (tid & 7)*8;
            const float* src = W + (long)(n0 + col)*K + kc*64 + k8;
            *(float4*)(ws + col*64 + k8)     = *(const float4*)(src);
            *(float4*)(ws + col*64 + k8 + 4) = *(const float4*)(src + 4);
        }
        {   // stage A transposed: as[k][m]
            const int m = tid >> 2, j4 = (tid & 3)*16;
            #pragma unroll
            for (int i4 = 0; i4 < 4; ++i4) {
                const int kk = kc*64 + j4 + i4*4;
                const float* srcA;
                if (MODE == 0) srcA = (kk < 256) ? (A + (long)m*256 + kk)
                                                 : (A + 16384 + (long)m*256 + kk - 256);
                else           srcA = A + (long)m*K + kk;
                float4 v = *(const float4*)srcA;
                as[(j4 + i4*4 + 0)*64 + m] = v.x;
                as[(j4 + i4*4 + 1)*64 + m] = v.y;
                as[(j4 + i4*4 + 2)*64 + m] = v.z;
                as[(j4 + i4*4 + 3)*64 + m] = v.w;
            }
        }
        __syncthreads();
        #pragma unroll 4
        for (int k4 = 0; k4 < 64; k4 += 4) {
            float a0[4], a1[4];
            #pragma unroll
            for (int i = 0; i < 4; ++i) {
                a0[i] = as[(k4+i)*64 + m2];
                a1[i] = as[(k4+i)*64 + m2 + 32];
            }
            #pragma unroll
            for (int j = 0; j < 4; ++j) {
                const float4 wv = *(const float4*)(ws + (ndg*4 + j)*64 + k4);
                acc[0][j] += a0[0]*wv.x + a0[1]*wv.y + a0[2]*wv.z + a0[3]*wv.w;
                acc[1][j] += a1[0]*wv.x + a1[1]*wv.y + a1[2]*wv.z + a1[3]*wv.w;
            }
        }
    }
    if (MODE == 1) {                       // res + relu, then fused BatchNorm
        float vv[2][4];
        #pragma unroll
        for (int i = 0; i < 2; ++i)
            #pragma unroll
            for (int j = 0; j < 4; ++j) {
                const int m = m2 + i*32, nn = n0 + ndg*4 + j;
                vv[i][j] = res[(long)m*1024 + nn] + fmaxf(acc[i][j] + bias[nn], 0.f);
            }
        __syncthreads();                    // as[] compute reads done
        #pragma unroll
        for (int i = 0; i < 2; ++i)
            #pragma unroll
            for (int j = 0; j < 4; ++j)
                as[(m2 + i*32)*33 + ndg*4 + j] = vv[i][j];   // stride 33: skewed banks
        __syncthreads();
        if (tid < 32) {
            float s = 0.f, ss = 0.f;
            #pragma unroll 4
            for (int m = 0; m < 64; ++m) {
                float x = as[m*33 + tid];
                s += x; ss += x*x;
            }
            const float mu = s * (1.f/64.f);
            mus[tid] = mu;
            rss[tid] = rsqrtf(ss * (1.f/64.f) - mu*mu + 1e-5f);
        }
        __syncthreads();
        #pragma unroll
        for (int i = 0; i < 2; ++i)
            #pragma unroll
            for (int j = 0; j < 4; ++j) {
                const int m = m2 + i*32, cl = ndg*4 + j, nn = n0 + cl;
                out[(long)m*Nst + nn] = (vv[i][j] - mus[cl]) * rss[cl] * bng[nn] + bnb[nn];
            }
        return;
    }
    #pragma unroll
    for (int i = 0; i < 2; ++i) {
        const int m = m2 + i*32;
        #pragma unroll
        for (int j = 0; j < 4; ++j) {
            const int nn = n0 + ndg*4 + j;
            float v = acc[i][j] + bias[nn];
            if (MODE == 0) v = 0.5f * v * (1.0f + erff(v * 0.7071067811865475f));
            else           v = fmaxf(v, 0.f);
            out[(long)m*Nst + nn] = v;
        }
    }
}

// ---------------------------------------------------------- count -----------
__global__ void k_count(const float* __restrict__ scores, float* __restrict__ outc)
{
    const int row = blockIdx.x, tid = threadIdx.x;
    const float* p = scores + (long)row*32000;
    int cnt = 0;
    for (int i = tid; i < 32000; i += 256)
        cnt += ((double)p[i] > 0.6400000000000001) ? 1 : 0;
    __shared__ int red[256];
    red[tid] = cnt; __syncthreads();
    for (int off = 128; off > 0; off >>= 1) {
        if (tid < off) red[tid] += red[tid + off];
        __syncthreads();
    }
    if (tid == 0) outc[row] = (float)(red[0] < 1 ? 1 : red[0]);
}

// ---------------------------------------------------------- launch ----------
extern "C" void kernel_launch(void* const* d_in, const int* in_sizes, int n_in,
                              void* d_out, int out_size, void* d_ws, size_t ws_size,
                              hipStream_t stream)
{
    const float* x1    = (const float*)d_in[0];
    const float* x2    = (const float*)d_in[1];
    const float* Wih0  = (const float*)d_in[2];
    const float* Whh0  = (const float*)d_in[3];
    const float* bih0  = (const float*)d_in[4];
    const float* bhh0  = (const float*)d_in[5];
    const float* Wih1  = (const float*)d_in[6];
    const float* Whh1  = (const float*)d_in[7];
    const float* bih1  = (const float*)d_in[8];
    const float* bhh1  = (const float*)d_in[9];
    const float* fc1_w = (const float*)d_in[10];
    const float* fc1_b = (const float*)d_in[11];
    const float* fc2_w = (const float*)d_in[12];
    const float* fc2_b = (const float*)d_in[13];
    const float* fc3_w = (const float*)d_in[14];
    const float* fc3_b = (const float*)d_in[15];
    const float* bn_g  = (const float*)d_in[16];
    const float* bn_b  = (const float*)d_in[17];
    float* out = (float*)d_out;

    char* ws = (char*)d_ws;
    f16*   x16   = (f16*)(ws);                // 2,097,152 B
    f16*   w16   = (f16*)(ws + 2097152);      // 1,703,936 B
    float* bsum  = (float*)(ws + 3801088);    // 8,192 B
    int*   flags = (int*)(ws + 3809280);      // 256 B
    float* enc   = (float*)(ws + 3809536);    // 131,072 B  [2][64][256]
    f16*   h0s   = (f16*)(ws + 3940608);      // 8,388,608 B  [128][128][256] step-major
    f16*   xg0   = (f16*)(ws + 12329216);     // 33,554,432 B [128 chains][128][1024]
    f16*   xg1   = (f16*)(ws + 45883648);     // 33,554,432 B (ends 79,438,080)
    float* h1    = (float*)(ws + 12329216);   // overlay xg0 region (dead after mega)
    float* h3    = (float*)(ws + 12591360);

    k_convert<<<2048, 256, 0, stream>>>(x1,x2,Wih0,Whh0,bih0,bhh0,Wih1,Whh1,bih1,bhh1,
                                        x16, w16, bsum, flags);
    // xg0 = x @ Wih0^T + (bih0+bhh0)  -> f16 gate-interleaved
    k_proj<64><<<dim3(128,8), 512, 0, stream>>>(x16, w16, bsum, xg0);
    // pipelined layer0 | xg1-projection | layer1
    k_mega<<<24, 512, 0, stream>>>(w16, xg0, xg1, h0s, bsum + 1024, enc, flags);
    // head (fc2 has BN fused)
    k_fc<512,0><<<32, 256, 0, stream>>>(enc, fc1_w, fc1_b, nullptr, nullptr, nullptr, h1, 1024);
    k_fc<1024,1><<<32, 256, 0, stream>>>(h1, fc2_w, fc2_b, h1, bn_g, bn_b, h3, 1024);
    k_fc<1024,2><<<1000, 256, 0, stream>>>(h3, fc3_w, fc3_b, nullptr, nullptr, nullptr, out, 32000);
    k_count<<<64, 256, 0, stream>>>(out, out + 2048000);
}